// Round 13
// baseline (133.642 us; speedup 1.0000x reference)
//
#include <hip/hip_runtime.h>
#include <hip/hip_bf16.h>

// Problem constants
// B=32768, P=8; aff/mat vocab 16 -> 256 (aff,mat) pairs
// part table: 256 pairs x 256 outputs (bf16)
// obj GEMM: pooled[B,256] @ W_obj[:,192:448]^T
//
// main_kernel: 512 blocks x 1024 threads, 64 rows/block (4 tiles of 16).
// Persistent B in VGPR; cat tables staged to LDS as bf16 (59 KB) so TWO
// blocks fit per CU -> cross-block overlap hides barrier stalls.

typedef float          f32x4  __attribute__((ext_vector_type(4)));
typedef short          s16x8  __attribute__((ext_vector_type(8)));
typedef unsigned short u16x8  __attribute__((ext_vector_type(8)));
typedef unsigned short u16x4  __attribute__((ext_vector_type(4)));

__device__ __forceinline__ unsigned short f2bf_rne(float x) {
    unsigned u = __float_as_uint(x);
    u += 0x7FFFu + ((u >> 16) & 1u);
    return (unsigned short)(u >> 16);
}
__device__ __forceinline__ float bf2f(unsigned short s) {
    return __uint_as_float(((unsigned)s) << 16);
}

// ws layout (bytes)
#define WS_PART_TABLE 0          // 256*256 short = 131072
#define WS_WP2T       131072     // 256*256 short = 131072  (W_obj[:,192:448] as [n][k], bf16)
#define WS_CATB       262144     // 112*264 bf16 rows: task[0..15]|obj[16..79]|state[80..111]
                                 //   (b_obj folded into task rows; stride 264)
// total = 262144 + 59136 = 321280 bytes

__global__ __launch_bounds__(256) void precompute_kernel(
    const float* __restrict__ aff_emb, const float* __restrict__ mat_emb,
    const float* __restrict__ task_emb, const float* __restrict__ obj_emb,
    const float* __restrict__ state_emb,
    const float* __restrict__ W_part, const float* __restrict__ b_part,
    const float* __restrict__ W_obj, const float* __restrict__ b_obj,
    char* __restrict__ ws)
{
    short* part_table = (short*)(ws + WS_PART_TABLE);
    short* wp2t       = (short*)(ws + WS_WP2T);
    short* catb       = (short*)(ws + WS_CATB);

    int bid = blockIdx.x, tid = threadIdx.x;
    __shared__ float rowv[128];

    if (bid < 256) {
        // part table: pair = a*16+m
        int a = bid >> 4, m = bid & 15;
        if (tid < 64)       rowv[tid] = aff_emb[a*64 + tid];
        else if (tid < 128) rowv[tid] = mat_emb[m*64 + (tid-64)];
        __syncthreads();
        float s = b_part[tid];
        const float* w = &W_part[tid*128];
        #pragma unroll
        for (int k = 0; k < 128; k += 4) {
            float4 wv = *(const float4*)&w[k];
            s += rowv[k]*wv.x + rowv[k+1]*wv.y + rowv[k+2]*wv.z + rowv[k+3]*wv.w;
        }
        part_table[bid*256 + tid] = (short)f2bf_rne(fmaxf(s, 0.f));
    } else if (bid < 368) {
        // categorical tables -> bf16, row rr in [0,112), stride 264
        int rr = bid - 256;
        const float* emb; int koff;
        if (rr < 16)      { emb = &task_emb[rr*64];       koff = 0;   }
        else if (rr < 80) { emb = &obj_emb[(rr-16)*64];   koff = 64;  }
        else              { emb = &state_emb[(rr-80)*64]; koff = 128; }
        if (tid < 64) rowv[tid] = emb[tid];
        __syncthreads();
        float s = (rr < 16) ? b_obj[tid] : 0.f;
        const float* w = &W_obj[tid*448 + koff];
        #pragma unroll
        for (int k = 0; k < 64; k += 4) {
            float4 wv = *(const float4*)&w[k];
            s += rowv[k]*wv.x + rowv[k+1]*wv.y + rowv[k+2]*wv.z + rowv[k+3]*wv.w;
        }
        catb[rr*264 + tid] = (short)f2bf_rne(s);
    } else {
        // W_obj[:,192:448] -> wp2t[n][k] bf16
        int n = bid - 368;
        wp2t[n*256 + tid] = (short)f2bf_rne(W_obj[n*448 + 192 + tid]);
    }
}

__global__ __launch_bounds__(1024, 8) void main_kernel(
    const int* __restrict__ aff_idx, const int* __restrict__ mat_idx,
    const int* __restrict__ task_idx, const int* __restrict__ obj_idx,
    const int* __restrict__ state_idx,
    const char* __restrict__ ws, float* __restrict__ out)
{
    const short* part_table = (const short*)(ws + WS_PART_TABLE);
    const short* wp2t       = (const short*)(ws + WS_WP2T);

    // LDS: 59136 + 8448 + 2048 + 768 = 70400 B (68.75 KiB) -> 2 blocks/CU
    __shared__ short catLb[112*264];   // bf16 cat rows, stride 264
    __shared__ short pooled[16*264];   // 16 rows x 256 elems, stride 264
    __shared__ int   pair_all[64*8];   // part_table element offsets
    __shared__ int   tos_all[3*64];    // task/obj/state per row

    int tid  = threadIdx.x;
    int wv   = tid >> 6, lane = tid & 63;
    int l15  = lane & 15, l4 = lane >> 4;
    int row0 = blockIdx.x * 64;

    // ---- stage cat tables: 59136 B = 3696 x 16B chunks
    {
        const u16x8* csrc = (const u16x8*)(ws + WS_CATB);
        u16x8* cdst = (u16x8*)catLb;
        #pragma unroll
        for (int k = 0; k < 3; ++k)
            cdst[tid + k*1024] = csrc[tid + k*1024];
        if (tid < 624)
            cdst[tid + 3*1024] = csrc[tid + 3*1024];
    }
    // ---- stage indices: 64 rows x 8 parts = 512; tos 3x64 = 192
    if (tid < 512) {
        int a = aff_idx[row0*8 + tid];
        int m = mat_idx[row0*8 + tid];
        pair_all[tid] = (a*16 + m) * 256;
    } else if (tid < 704) {
        int u = tid - 512;
        int wh = u >> 6, r = u & 63;
        const int* p = (wh == 0) ? task_idx : (wh == 1) ? obj_idx : state_idx;
        tos_all[wh*64 + r] = p[row0 + r];
    }

    // ---- persistent B fragments: wave wv owns output cols [wv*16, wv*16+16)
    // B[k][n]: col = lane&15 (n = wv*16+l15), k = ks*32 + (lane>>4)*8 + j
    s16x8 bfrag[8];
    #pragma unroll
    for (int ks = 0; ks < 8; ++ks)
        bfrag[ks] = *(const s16x8*)&wp2t[(wv*16 + l15)*256 + ks*32 + l4*8];

    __syncthreads();

    // ---- pooling prefetch for tile 0: thread (pr = tid>>6, pe = tid&63)
    // covers elems [pe*4, pe*4+4) of row pr (u16x4 = 8B loads)
    int pr = tid >> 6, pe = tid & 63;
    u16x4 pl[8];
    #pragma unroll
    for (int p = 0; p < 8; ++p)
        pl[p] = *(const u16x4*)&part_table[pair_all[pr*8 + p] + pe*4];

    for (int t = 0; t < 4; ++t) {
        // reduce prefetched pool loads; write pooled.
        // ReLU'd bf16 is non-negative: u16 bit order == float order (exact).
        u16x4 mx = pl[0];
        #pragma unroll
        for (int p = 1; p < 8; ++p) mx = __builtin_elementwise_max(mx, pl[p]);
        *(u16x4*)&pooled[pr*264 + pe*4] = mx;
        __syncthreads();

        // prefetch next tile's pool loads (in flight during MFMA + epilogue)
        if (t < 3) {
            #pragma unroll
            for (int p = 0; p < 8; ++p)
                pl[p] = *(const u16x4*)&part_table[pair_all[((t+1)*16 + pr)*8 + p] + pe*4];
        }

        // MFMA: D[16 rows][16 cols]; A row = lane&15, k = (lane>>4)*8+j
        f32x4 acc = (f32x4){0.f, 0.f, 0.f, 0.f};
        #pragma unroll
        for (int ks = 0; ks < 8; ++ks) {
            s16x8 af = *(const s16x8*)&pooled[l15*264 + ks*32 + l4*8];
            acc = __builtin_amdgcn_mfma_f32_16x16x32_bf16(af, bfrag[ks], acc, 0, 0, 0);
        }

        // epilogue: C/D col = lane&15, row = (lane>>4)*4 + reg; cat from LDS bf16
        int col = wv*16 + l15;
        #pragma unroll
        for (int reg = 0; reg < 4; ++reg) {
            int rl = l4*4 + reg;
            int ti = tos_all[t*16 + rl];
            int oi = tos_all[64 + t*16 + rl];
            int si = tos_all[128 + t*16 + rl];
            float v = acc[reg] + bf2f((unsigned short)catLb[ti*264 + col])
                               + bf2f((unsigned short)catLb[(16 + oi)*264 + col])
                               + bf2f((unsigned short)catLb[(80 + si)*264 + col]);
            out[(row0 + t*16 + rl)*256 + col] = fmaxf(v, 0.f);
        }
        __syncthreads();   // all waves done reading pooled before next overwrite
    }
}

extern "C" void kernel_launch(void* const* d_in, const int* in_sizes, int n_in,
                              void* d_out, int out_size, void* d_ws, size_t ws_size,
                              hipStream_t stream) {
    const int*   aff_idx   = (const int*)d_in[0];
    const int*   mat_idx   = (const int*)d_in[1];
    const int*   task_idx  = (const int*)d_in[2];
    const int*   obj_idx   = (const int*)d_in[3];
    const int*   state_idx = (const int*)d_in[4];
    const float* aff_emb   = (const float*)d_in[5];
    const float* mat_emb   = (const float*)d_in[6];
    const float* task_emb  = (const float*)d_in[7];
    const float* obj_emb   = (const float*)d_in[8];
    const float* state_emb = (const float*)d_in[9];
    const float* W_part    = (const float*)d_in[10];
    const float* b_part    = (const float*)d_in[11];
    const float* W_obj     = (const float*)d_in[12];
    const float* b_obj     = (const float*)d_in[13];

    precompute_kernel<<<624, 256, 0, stream>>>(
        aff_emb, mat_emb, task_emb, obj_emb, state_emb,
        W_part, b_part, W_obj, b_obj, (char*)d_ws);

    main_kernel<<<512, 1024, 0, stream>>>(
        aff_idx, mat_idx, task_idx, obj_idx, state_idx,
        (const char*)d_ws, (float*)d_out);
}

// Round 15
// 116.751 us; speedup vs baseline: 1.1447x; 1.1447x over previous
//
#include <hip/hip_runtime.h>
#include <hip/hip_bf16.h>

// Problem constants
// B=32768, P=8; aff/mat vocab 16 -> 256 (aff,mat) pairs
// part table: 256 pairs x 256 outputs (bf16)
// obj GEMM: pooled[B,256] @ W_obj[:,192:448]^T
//
// main_kernel: 256 blocks x 1024 threads, 128 rows/block (8 tiles of 16).
// Persistent B in VGPR; bf16 cat tables staged to LDS (59 KB); pooling
// prefetched one tile ahead. launch_bounds(1024,4): 128-VGPR budget --
// (1024,8) forced 32 VGPR and spilled catastrophically (R13: WRITE 90MB).

typedef float          f32x4  __attribute__((ext_vector_type(4)));
typedef short          s16x8  __attribute__((ext_vector_type(8)));
typedef unsigned short u16x8  __attribute__((ext_vector_type(8)));
typedef unsigned short u16x4  __attribute__((ext_vector_type(4)));

__device__ __forceinline__ unsigned short f2bf_rne(float x) {
    unsigned u = __float_as_uint(x);
    u += 0x7FFFu + ((u >> 16) & 1u);
    return (unsigned short)(u >> 16);
}
__device__ __forceinline__ float bf2f(unsigned short s) {
    return __uint_as_float(((unsigned)s) << 16);
}

// ws layout (bytes)
#define WS_PART_TABLE 0          // 256*256 short = 131072
#define WS_WP2T       131072     // 256*256 short = 131072  (W_obj[:,192:448] as [n][k], bf16)
#define WS_CATB       262144     // 112*264 bf16 rows: task[0..15]|obj[16..79]|state[80..111]
                                 //   (b_obj folded into task rows; stride 264)
// total = 262144 + 59136 = 321280 bytes

__global__ __launch_bounds__(256) void precompute_kernel(
    const float* __restrict__ aff_emb, const float* __restrict__ mat_emb,
    const float* __restrict__ task_emb, const float* __restrict__ obj_emb,
    const float* __restrict__ state_emb,
    const float* __restrict__ W_part, const float* __restrict__ b_part,
    const float* __restrict__ W_obj, const float* __restrict__ b_obj,
    char* __restrict__ ws)
{
    short* part_table = (short*)(ws + WS_PART_TABLE);
    short* wp2t       = (short*)(ws + WS_WP2T);
    short* catb       = (short*)(ws + WS_CATB);

    int bid = blockIdx.x, tid = threadIdx.x;
    __shared__ float rowv[128];

    if (bid < 256) {
        // part table: pair = a*16+m
        int a = bid >> 4, m = bid & 15;
        if (tid < 64)       rowv[tid] = aff_emb[a*64 + tid];
        else if (tid < 128) rowv[tid] = mat_emb[m*64 + (tid-64)];
        __syncthreads();
        float s = b_part[tid];
        const float* w = &W_part[tid*128];
        #pragma unroll
        for (int k = 0; k < 128; k += 4) {
            float4 wv = *(const float4*)&w[k];
            s += rowv[k]*wv.x + rowv[k+1]*wv.y + rowv[k+2]*wv.z + rowv[k+3]*wv.w;
        }
        part_table[bid*256 + tid] = (short)f2bf_rne(fmaxf(s, 0.f));
    } else if (bid < 368) {
        // categorical tables -> bf16, row rr in [0,112), stride 264
        int rr = bid - 256;
        const float* emb; int koff;
        if (rr < 16)      { emb = &task_emb[rr*64];       koff = 0;   }
        else if (rr < 80) { emb = &obj_emb[(rr-16)*64];   koff = 64;  }
        else              { emb = &state_emb[(rr-80)*64]; koff = 128; }
        if (tid < 64) rowv[tid] = emb[tid];
        __syncthreads();
        float s = (rr < 16) ? b_obj[tid] : 0.f;
        const float* w = &W_obj[tid*448 + koff];
        #pragma unroll
        for (int k = 0; k < 64; k += 4) {
            float4 wv = *(const float4*)&w[k];
            s += rowv[k]*wv.x + rowv[k+1]*wv.y + rowv[k+2]*wv.z + rowv[k+3]*wv.w;
        }
        catb[rr*264 + tid] = (short)f2bf_rne(s);
    } else {
        // W_obj[:,192:448] -> wp2t[n][k] bf16
        int n = bid - 368;
        wp2t[n*256 + tid] = (short)f2bf_rne(W_obj[n*448 + 192 + tid]);
    }
}

__global__ __launch_bounds__(1024, 4) void main_kernel(
    const int* __restrict__ aff_idx, const int* __restrict__ mat_idx,
    const int* __restrict__ task_idx, const int* __restrict__ obj_idx,
    const int* __restrict__ state_idx,
    const char* __restrict__ ws, float* __restrict__ out)
{
    const short* part_table = (const short*)(ws + WS_PART_TABLE);
    const short* wp2t       = (const short*)(ws + WS_WP2T);

    // LDS: 59136 + 8448 + 4096 + 1536 = 73216 B (71.5 KiB)
    __shared__ short catLb[112*264];   // bf16 cat rows, stride 264
    __shared__ short pooled[16*264];   // 16 rows x 256 elems, stride 264
    __shared__ int   pair_all[128*8];  // part_table element offsets, all 128 rows
    __shared__ int   tos_all[3*128];   // task/obj/state per row

    int tid  = threadIdx.x;
    int wv   = tid >> 6, lane = tid & 63;
    int l15  = lane & 15, l4 = lane >> 4;
    int row0 = blockIdx.x * 128;

    // ---- stage cat tables: 59136 B = 3696 x 16B chunks
    {
        const u16x8* csrc = (const u16x8*)(ws + WS_CATB);
        u16x8* cdst = (u16x8*)catLb;
        #pragma unroll
        for (int k = 0; k < 3; ++k)
            cdst[tid + k*1024] = csrc[tid + k*1024];
        if (tid < 624)
            cdst[tid + 3*1024] = csrc[tid + 3*1024];
    }
    // ---- stage indices: 1024 threads == 128 rows x 8 parts exactly
    {
        int a = aff_idx[row0*8 + tid];
        int m = mat_idx[row0*8 + tid];
        pair_all[tid] = (a*16 + m) * 256;
    }
    if (tid < 384) {
        int wh = tid >> 7, r = tid & 127;
        const int* p = (wh == 0) ? task_idx : (wh == 1) ? obj_idx : state_idx;
        tos_all[wh*128 + r] = p[row0 + r];
    }

    // ---- persistent B fragments: wave wv owns output cols [wv*16, wv*16+16)
    // B[k][n]: col = lane&15 (n = wv*16+l15), k = ks*32 + (lane>>4)*8 + j
    s16x8 bfrag[8];
    #pragma unroll
    for (int ks = 0; ks < 8; ++ks)
        bfrag[ks] = *(const s16x8*)&wp2t[(wv*16 + l15)*256 + ks*32 + l4*8];

    __syncthreads();

    // ---- pooling prefetch for tile 0: thread (pr = tid>>6, pe = tid&63)
    // covers elems [pe*4, pe*4+4) of row pr (u16x4 = 8B loads)
    int pr = tid >> 6, pe = tid & 63;
    u16x4 pl[8];
    #pragma unroll
    for (int p = 0; p < 8; ++p)
        pl[p] = *(const u16x4*)&part_table[pair_all[pr*8 + p] + pe*4];

    for (int t = 0; t < 8; ++t) {
        // reduce prefetched pool loads; write pooled.
        // ReLU'd bf16 is non-negative: u16 bit order == float order (exact).
        u16x4 mx = pl[0];
        #pragma unroll
        for (int p = 1; p < 8; ++p) mx = __builtin_elementwise_max(mx, pl[p]);
        *(u16x4*)&pooled[pr*264 + pe*4] = mx;
        __syncthreads();

        // prefetch next tile's pool loads (in flight during MFMA + epilogue)
        if (t < 7) {
            #pragma unroll
            for (int p = 0; p < 8; ++p)
                pl[p] = *(const u16x4*)&part_table[pair_all[((t+1)*16 + pr)*8 + p] + pe*4];
        }

        // MFMA: D[16 rows][16 cols]; A row = lane&15, k = (lane>>4)*8+j
        f32x4 acc = (f32x4){0.f, 0.f, 0.f, 0.f};
        #pragma unroll
        for (int ks = 0; ks < 8; ++ks) {
            s16x8 af = *(const s16x8*)&pooled[l15*264 + ks*32 + l4*8];
            acc = __builtin_amdgcn_mfma_f32_16x16x32_bf16(af, bfrag[ks], acc, 0, 0, 0);
        }

        // epilogue: C/D col = lane&15, row = (lane>>4)*4 + reg; cat from LDS bf16
        int col = wv*16 + l15;
        #pragma unroll
        for (int reg = 0; reg < 4; ++reg) {
            int rl = l4*4 + reg;
            int ti = tos_all[t*16 + rl];
            int oi = tos_all[128 + t*16 + rl];
            int si = tos_all[256 + t*16 + rl];
            float v = acc[reg] + bf2f((unsigned short)catLb[ti*264 + col])
                               + bf2f((unsigned short)catLb[(16 + oi)*264 + col])
                               + bf2f((unsigned short)catLb[(80 + si)*264 + col]);
            out[(row0 + t*16 + rl)*256 + col] = fmaxf(v, 0.f);
        }
        __syncthreads();   // all waves done reading pooled before next overwrite
    }
}

extern "C" void kernel_launch(void* const* d_in, const int* in_sizes, int n_in,
                              void* d_out, int out_size, void* d_ws, size_t ws_size,
                              hipStream_t stream) {
    const int*   aff_idx   = (const int*)d_in[0];
    const int*   mat_idx   = (const int*)d_in[1];
    const int*   task_idx  = (const int*)d_in[2];
    const int*   obj_idx   = (const int*)d_in[3];
    const int*   state_idx = (const int*)d_in[4];
    const float* aff_emb   = (const float*)d_in[5];
    const float* mat_emb   = (const float*)d_in[6];
    const float* task_emb  = (const float*)d_in[7];
    const float* obj_emb   = (const float*)d_in[8];
    const float* state_emb = (const float*)d_in[9];
    const float* W_part    = (const float*)d_in[10];
    const float* b_part    = (const float*)d_in[11];
    const float* W_obj     = (const float*)d_in[12];
    const float* b_obj     = (const float*)d_in[13];

    precompute_kernel<<<624, 256, 0, stream>>>(
        aff_emb, mat_emb, task_emb, obj_emb, state_emb,
        W_part, b_part, W_obj, b_obj, (char*)d_ws);

    main_kernel<<<256, 1024, 0, stream>>>(
        aff_idx, mat_idx, task_idx, obj_idx, state_idx,
        (const char*)d_ws, (float*)d_out);
}

// Round 16
// 115.944 us; speedup vs baseline: 1.1526x; 1.0070x over previous
//
#include <hip/hip_runtime.h>
#include <hip/hip_bf16.h>

// Problem constants
// B=32768, P=8; aff/mat vocab 16 -> 256 (aff,mat) pairs
// part table: 256 pairs x 256 outputs (bf16)
// obj GEMM: pooled[B,256] @ W_obj[:,192:448]^T
//
// main_kernel: 512 blocks x 512 threads (8 waves), 64 rows/block (4 tiles).
// LDS 70.4 KB -> TWO blocks/CU (141 KB < 160 KB) for cross-block overlap of
// barrier drains. Each wave owns 2 column-tiles (bfrag[2][8] = 64 VGPR).
// R13 lesson: never force VGPR below live state (32-reg cap -> 90 MB spills).

typedef float          f32x4  __attribute__((ext_vector_type(4)));
typedef short          s16x8  __attribute__((ext_vector_type(8)));
typedef unsigned short u16x8  __attribute__((ext_vector_type(8)));

__device__ __forceinline__ unsigned short f2bf_rne(float x) {
    unsigned u = __float_as_uint(x);
    u += 0x7FFFu + ((u >> 16) & 1u);
    return (unsigned short)(u >> 16);
}
__device__ __forceinline__ float bf2f(unsigned short s) {
    return __uint_as_float(((unsigned)s) << 16);
}

// ws layout (bytes)
#define WS_PART_TABLE 0          // 256*256 short = 131072
#define WS_WP2T       131072     // 256*256 short = 131072  (W_obj[:,192:448] as [n][k], bf16)
#define WS_CATB       262144     // 112*264 bf16 rows: task[0..15]|obj[16..79]|state[80..111]
                                 //   (b_obj folded into task rows; stride 264)
// total = 262144 + 59136 = 321280 bytes

__global__ __launch_bounds__(256) void precompute_kernel(
    const float* __restrict__ aff_emb, const float* __restrict__ mat_emb,
    const float* __restrict__ task_emb, const float* __restrict__ obj_emb,
    const float* __restrict__ state_emb,
    const float* __restrict__ W_part, const float* __restrict__ b_part,
    const float* __restrict__ W_obj, const float* __restrict__ b_obj,
    char* __restrict__ ws)
{
    short* part_table = (short*)(ws + WS_PART_TABLE);
    short* wp2t       = (short*)(ws + WS_WP2T);
    short* catb       = (short*)(ws + WS_CATB);

    int bid = blockIdx.x, tid = threadIdx.x;
    __shared__ float rowv[128];

    if (bid < 256) {
        // part table: pair = a*16+m
        int a = bid >> 4, m = bid & 15;
        if (tid < 64)       rowv[tid] = aff_emb[a*64 + tid];
        else if (tid < 128) rowv[tid] = mat_emb[m*64 + (tid-64)];
        __syncthreads();
        float s = b_part[tid];
        const float* w = &W_part[tid*128];
        #pragma unroll
        for (int k = 0; k < 128; k += 4) {
            float4 wv = *(const float4*)&w[k];
            s += rowv[k]*wv.x + rowv[k+1]*wv.y + rowv[k+2]*wv.z + rowv[k+3]*wv.w;
        }
        part_table[bid*256 + tid] = (short)f2bf_rne(fmaxf(s, 0.f));
    } else if (bid < 368) {
        // categorical tables -> bf16, row rr in [0,112), stride 264
        int rr = bid - 256;
        const float* emb; int koff;
        if (rr < 16)      { emb = &task_emb[rr*64];       koff = 0;   }
        else if (rr < 80) { emb = &obj_emb[(rr-16)*64];   koff = 64;  }
        else              { emb = &state_emb[(rr-80)*64]; koff = 128; }
        if (tid < 64) rowv[tid] = emb[tid];
        __syncthreads();
        float s = (rr < 16) ? b_obj[tid] : 0.f;
        const float* w = &W_obj[tid*448 + koff];
        #pragma unroll
        for (int k = 0; k < 64; k += 4) {
            float4 wv = *(const float4*)&w[k];
            s += rowv[k]*wv.x + rowv[k+1]*wv.y + rowv[k+2]*wv.z + rowv[k+3]*wv.w;
        }
        catb[rr*264 + tid] = (short)f2bf_rne(s);
    } else {
        // W_obj[:,192:448] -> wp2t[n][k] bf16
        int n = bid - 368;
        wp2t[n*256 + tid] = (short)f2bf_rne(W_obj[n*448 + 192 + tid]);
    }
}

__global__ __launch_bounds__(512, 4) void main_kernel(
    const int* __restrict__ aff_idx, const int* __restrict__ mat_idx,
    const int* __restrict__ task_idx, const int* __restrict__ obj_idx,
    const int* __restrict__ state_idx,
    const char* __restrict__ ws, float* __restrict__ out)
{
    const short* part_table = (const short*)(ws + WS_PART_TABLE);
    const short* wp2t       = (const short*)(ws + WS_WP2T);

    // LDS: 59136 + 8448 + 2048 + 768 = 70400 B -> 2 blocks/CU
    __shared__ short catLb[112*264];   // bf16 cat rows, stride 264
    __shared__ short pooled[16*264];   // 16 rows x 256 elems, stride 264
    __shared__ int   pair_all[64*8];   // part_table element offsets
    __shared__ int   tos_all[3*64];    // task/obj/state per row

    int tid  = threadIdx.x;
    int wv   = tid >> 6, lane = tid & 63;
    int l15  = lane & 15, l4 = lane >> 4;
    int row0 = blockIdx.x * 64;

    // ---- stage cat tables: 59136 B = 3696 x 16B chunks, 512 threads
    {
        const u16x8* csrc = (const u16x8*)(ws + WS_CATB);
        u16x8* cdst = (u16x8*)catLb;
        #pragma unroll
        for (int k = 0; k < 7; ++k)
            cdst[tid + k*512] = csrc[tid + k*512];
        if (tid < 112)
            cdst[tid + 7*512] = csrc[tid + 7*512];
    }
    // ---- stage indices: 64 rows x 8 parts = 512 = one per thread
    {
        int a = aff_idx[row0*8 + tid];
        int m = mat_idx[row0*8 + tid];
        pair_all[tid] = (a*16 + m) * 256;
    }
    if (tid < 192) {
        int wh = tid >> 6, r = tid & 63;
        const int* p = (wh == 0) ? task_idx : (wh == 1) ? obj_idx : state_idx;
        tos_all[wh*64 + r] = p[row0 + r];
    }

    // ---- persistent B fragments: wave wv owns cols [wv*32, wv*32+32) (2 n-tiles)
    // B[k][n]: col = lane&15 within n-tile, k = ks*32 + (lane>>4)*8 + j
    s16x8 bfrag[2][8];
    #pragma unroll
    for (int nt = 0; nt < 2; ++nt)
        #pragma unroll
        for (int ks = 0; ks < 8; ++ks)
            bfrag[nt][ks] = *(const s16x8*)&wp2t[(wv*32 + nt*16 + l15)*256 + ks*32 + l4*8];

    __syncthreads();

    // ---- pooling prefetch for tile 0: thread (pr = tid>>5, pe = tid&31)
    // covers elems [pe*8, pe*8+8) of row pr (u16x8 = 16B loads)
    int pr = tid >> 5, pe = tid & 31;
    u16x8 pl[8];
    #pragma unroll
    for (int p = 0; p < 8; ++p)
        pl[p] = *(const u16x8*)&part_table[pair_all[pr*8 + p] + pe*8];

    for (int t = 0; t < 4; ++t) {
        // reduce prefetched pool loads; write pooled.
        // ReLU'd bf16 is non-negative: u16 bit order == float order (exact).
        u16x8 mx = pl[0];
        #pragma unroll
        for (int p = 1; p < 8; ++p) mx = __builtin_elementwise_max(mx, pl[p]);
        *(u16x8*)&pooled[pr*264 + pe*8] = mx;
        __syncthreads();

        // prefetch next tile's pool loads
        if (t < 3) {
            #pragma unroll
            for (int p = 0; p < 8; ++p)
                pl[p] = *(const u16x8*)&part_table[pair_all[((t+1)*16 + pr)*8 + p] + pe*8];
        }

        // MFMA: A row = lane&15, k = (lane>>4)*8+j; one A-read feeds both n-tiles
        f32x4 acc[2];
        acc[0] = (f32x4){0.f, 0.f, 0.f, 0.f};
        acc[1] = (f32x4){0.f, 0.f, 0.f, 0.f};
        #pragma unroll
        for (int ks = 0; ks < 8; ++ks) {
            s16x8 af = *(const s16x8*)&pooled[l15*264 + ks*32 + l4*8];
            acc[0] = __builtin_amdgcn_mfma_f32_16x16x32_bf16(af, bfrag[0][ks], acc[0], 0, 0, 0);
            acc[1] = __builtin_amdgcn_mfma_f32_16x16x32_bf16(af, bfrag[1][ks], acc[1], 0, 0, 0);
        }

        // epilogue: C/D col = lane&15, row = (lane>>4)*4 + reg; cat from LDS bf16
        #pragma unroll
        for (int nt = 0; nt < 2; ++nt) {
            int col = wv*32 + nt*16 + l15;
            #pragma unroll
            for (int reg = 0; reg < 4; ++reg) {
                int rl = l4*4 + reg;
                int ti = tos_all[t*16 + rl];
                int oi = tos_all[64 + t*16 + rl];
                int si = tos_all[128 + t*16 + rl];
                float v = acc[nt][reg] + bf2f((unsigned short)catLb[ti*264 + col])
                                       + bf2f((unsigned short)catLb[(16 + oi)*264 + col])
                                       + bf2f((unsigned short)catLb[(80 + si)*264 + col]);
                out[(row0 + t*16 + rl)*256 + col] = fmaxf(v, 0.f);
            }
        }
        __syncthreads();   // all waves done reading pooled before next overwrite
    }
}

extern "C" void kernel_launch(void* const* d_in, const int* in_sizes, int n_in,
                              void* d_out, int out_size, void* d_ws, size_t ws_size,
                              hipStream_t stream) {
    const int*   aff_idx   = (const int*)d_in[0];
    const int*   mat_idx   = (const int*)d_in[1];
    const int*   task_idx  = (const int*)d_in[2];
    const int*   obj_idx   = (const int*)d_in[3];
    const int*   state_idx = (const int*)d_in[4];
    const float* aff_emb   = (const float*)d_in[5];
    const float* mat_emb   = (const float*)d_in[6];
    const float* task_emb  = (const float*)d_in[7];
    const float* obj_emb   = (const float*)d_in[8];
    const float* state_emb = (const float*)d_in[9];
    const float* W_part    = (const float*)d_in[10];
    const float* b_part    = (const float*)d_in[11];
    const float* W_obj     = (const float*)d_in[12];
    const float* b_obj     = (const float*)d_in[13];

    precompute_kernel<<<624, 256, 0, stream>>>(
        aff_emb, mat_emb, task_emb, obj_emb, state_emb,
        W_part, b_part, W_obj, b_obj, (char*)d_ws);

    main_kernel<<<512, 512, 0, stream>>>(
        aff_idx, mat_idx, task_idx, obj_idx, state_idx,
        (const char*)d_ws, (float*)d_out);
}